// Round 6
// baseline (165.553 us; speedup 1.0000x reference)
//
#include <hip/hip_runtime.h>
#include <math.h>

// KTVLoss: inputs out_l, out_r, input_i : (8,3,512,512) fp32. Output: 1 fp32 scalar.
//
// Sx = 10x10 box sum of |dI/dh| (502x503), Sy = box sum of |dI/dw| (503x502).
// Reference pairs them by FLAT index: Sx(i,j) with Sy(i,i+j) if i+j<502 else
// Sy(i+1,i+j-502). ratio = (SxL+SyL+SxR+SyR)/(SxI+SyI+1e-4), mean over 24*502*503.
// grad part (fp32, accuracy-critical): mean|GxL+GxR-GxI| + mean|GyL+GyR-GyI|.
// norm part carries a 1e-4 weight -> computed in packed f16 (error ~1e-5 abs).
//
// One block per (image, band of RB=24 Sx rows); 512 threads = 1 per column;
// 504 blocks, ~90 VGPR -> 2 blocks/CU -> ALL blocks co-resident (504<=512).
// Horizontal 10-window via full-wave DPP prefix scan on packed f16
// (row_shr:1/2/4/8 + row_bcast15/31), h = A[j+9]-A[j-1]; wave boundary
// (9 lanes) patched via tiny LDS array + readlane total. Vertical 10-window
// via f16x2 register ring (35 fully-unrolled steps => static slots).
// One barrier per step; all LDS write->read pairs barrier-separated.
//
// R4/R5 lesson: __launch_bounds__ 2nd arg empirically caps VGPR at 256/arg
// (8->32, 4->64) -> scratch spills (WRITE_SIZE 195/65 MB). NO launch_bounds:
// allocator takes its natural footprint, zero spill.

namespace {

constexpr int H = 512, W = 512;
constexpr int CX = W - 10 + 1;   // 503 Sx cols (Sy has 503 rows)
constexpr int CY = W - 10;       // 502 Sy cols
constexpr int RB = 24;           // Sx rows per band
constexpr int NBANDS = (CY + RB - 1) / RB;   // 21
constexpr int NIMG = 24;
constexpr int NBLOCKS = NIMG * NBANDS;       // 504

typedef __fp16 h2 __attribute__((ext_vector_type(2)));

__device__ __forceinline__ int h2i(h2 v) { int r; __builtin_memcpy(&r, &v, 4); return r; }
__device__ __forceinline__ h2 i2h(int v) { h2 r; __builtin_memcpy(&r, &v, 4); return r; }

template <int C, int RM>
__device__ __forceinline__ int dppmov(int v) {
  return __builtin_amdgcn_update_dpp(0, v, C, RM, 0xf, true);
}
// full 64-lane inclusive prefix sum of a f16x2 pack (pure VALU)
__device__ __forceinline__ h2 scan64(h2 v) {
  v += i2h(dppmov<0x111, 0xf>(h2i(v)));  // row_shr:1
  v += i2h(dppmov<0x112, 0xf>(h2i(v)));  // row_shr:2
  v += i2h(dppmov<0x114, 0xf>(h2i(v)));  // row_shr:4
  v += i2h(dppmov<0x118, 0xf>(h2i(v)));  // row_shr:8
  v += i2h(dppmov<0x142, 0xa>(h2i(v)));  // row_bcast15 -> rows 1,3
  v += i2h(dppmov<0x143, 0xc>(h2i(v)));  // row_bcast31 -> rows 2,3
  return v;
}
__device__ __forceinline__ float wshl1(float v) {  // lane i <- lane i+1
  return __int_as_float(__builtin_amdgcn_update_dpp(0, __float_as_int(v), 0x130, 0xf, 0xf, true));
}

}  // namespace

// One streaming step; S (step) and U (ring slot = S%10) are literals.
#define STEP(S, U)                                                                \
  {                                                                               \
    constexpr int s_ = (S);                                                       \
    const int r = i0 + s_;                                                        \
    const float xl = nL, xr = nR, xi = nI;                                        \
    const float x1l = mL, x1r = mR, x1i = mI;                                     \
    if (r + 1 < H) { /* prefetch next row (wave-uniform guard) */                 \
      nL = pL[offN]; nR = pR[offN]; nI = pI[offN];                                \
      if (lastlane) { mL = pL[offN + 1]; mR = pR[offN + 1]; mI = pI[offN + 1]; }  \
      offN += W;                                                                  \
    }                                                                             \
    float nxl = wshl1(xl), nxr = wshl1(xr), nxi = wshl1(xi);                      \
    if (lastlane) { nxl = x1l; nxr = x1r; nxi = x1i; }                            \
    const float gyl = nxl - xl, gyr = nxr - xr, gyi = nxi - xi;                   \
    const float gxl = xl - prevL, gxr = xr - prevR, gxi = xi - prevI;             \
    prevL = xl; prevR = xr; prevI = xi;                                           \
    if (r < gyEnd && j < W - 1) accGY += fabsf(gyl + gyr - gyi);                  \
    if (s_ > 0 && (r - 1) < gxEnd) accGX += fabsf(gxl + gxr - gxi);               \
    float yn = fabsf(gyl) + fabsf(gyr), yd = fabsf(gyi);                          \
    float xn = fabsf(gxl) + fabsf(gxr), xd = fabsf(gxi);                          \
    if (j == W - 1) { yn = 0.f; yd = 0.f; }                                       \
    if (r >= H) { yn = 0.f; yd = 0.f; xn = 0.f; xd = 0.f; }                       \
    const h2 Y = __builtin_amdgcn_cvt_pkrtz(yn, yd);                              \
    h2 X = (h2)(__fp16)0;                                                         \
    if (s_ != 0) X = __builtin_amdgcn_cvt_pkrtz(xn, xd);                          \
    const h2 AY = scan64(Y), AX = scan64(X);                                      \
    const h2 eY = i2h(dppmov<0x138, 0xf>(h2i(AY)));  /* A[j-1], wave_shr:1 */     \
    const h2 eX = i2h(dppmov<0x138, 0xf>(h2i(AX)));                               \
    const h2 TY = i2h(__builtin_amdgcn_readlane(h2i(AY), 63));                    \
    const h2 TX = i2h(__builtin_amdgcn_readlane(h2i(AX), 63));                    \
    h2 hY = i2h(__shfl(h2i(AY), lane9)) - eY;        /* A[j+9]-A[j-1] */          \
    h2 hX = i2h(__shfl(h2i(AX), lane9)) - eX;                                     \
    const h2 pY = TY - eY, pX = TX - eX;                                          \
    if (lane <= 8) bnd[s_ & 1][wv][lane] = make_int2(h2i(AY), h2i(AX));           \
    __syncthreads();                                                              \
    if (patch) { /* lanes 55..63: window spills into next wave */                 \
      const int2 Ap = bnd[s_ & 1][wv + 1][lane - 55];                             \
      hY = i2h(Ap.x) + pY;                                                        \
      hX = i2h(Ap.y) + pX;                                                        \
    }                                                                             \
    if (s_ >= 11) { /* runX pre-update == Sx row r-11; Sy rows r-11,r-10 ready */ \
      const int iX = r - 11;                                                      \
      if (iX < sxEnd && j < CX) {                                                 \
        int jy = iX + j, rw = iX;                                                 \
        if (jy >= CY) { jy -= CY; ++rw; }                                         \
        const h2 sy = i2h(syring[rw & 3][jy]);                                    \
        const float num = (float)runX.x + (float)sy.x;                            \
        const float den = (float)runX.y + (float)sy.y + 1e-4f;                    \
        accN += num * __builtin_amdgcn_rcpf(den);                                 \
      }                                                                           \
    }                                                                             \
    runY += hY - histY[U]; histY[U] = hY;                                         \
    runX += hX - histX[U]; histX[U] = hX;                                         \
    if (s_ >= 9) {                                                                \
      const int iY = r - 9;                                                       \
      if (iY <= sxEnd && j < CY) syring[iY & 3][j] = h2i(runY);                   \
    }                                                                             \
  }

__global__ void ktv_main(const float* __restrict__ L,
                         const float* __restrict__ R,
                         const float* __restrict__ I,
                         double* __restrict__ partial) {
  const int blk = blockIdx.x;
  const int img = blk / NBANDS;
  const int band = blk % NBANDS;
  const int i0 = band * RB;
  const int j = threadIdx.x;  // column
  const int lane = j & 63;
  const int wv = j >> 6;
  const int lane9 = lane + 9;
  const bool lastlane = (lane == 63) && (j < W - 1);
  const bool patch = (lane >= 55) && (wv < 7);

  const bool lastb = (band == NBANDS - 1);
  const int gyEnd = lastb ? H : (i0 + RB);        // Gy rows owned: [i0, gyEnd)
  const int gxEnd = lastb ? (H - 1) : (i0 + RB);  // Gx rows owned: [i0, gxEnd)
  const int sxEnd = lastb ? CY : (i0 + RB);       // Sx rows owned: [i0, sxEnd)

  const size_t base = (size_t)img * (H * W);
  const float* pL = L + base;
  const float* pR = R + base;
  const float* pI = I + base;

  __shared__ int syring[4][CY];    // completed Sy rows (f16x2 n,d), depth-4 ring
  __shared__ int2 bnd[2][8][9];    // per-wave lanes 0..8 scan prefix (Y,X packs)
  __shared__ float redN[8], redGX[8], redGY[8];

  h2 histY[10], histX[10];
#pragma unroll
  for (int t = 0; t < 10; ++t) { histY[t] = (h2)(__fp16)0; histX[t] = (h2)(__fp16)0; }
  h2 runY = (h2)(__fp16)0, runX = (h2)(__fp16)0;
  float accN = 0.f, accGX = 0.f, accGY = 0.f;
  float prevL = 0.f, prevR = 0.f, prevI = 0.f;

  // prologue: load row i0 (+ lane-63 col j+1 patch values)
  int offN = i0 * W + j;
  float nL = pL[offN], nR = pR[offN], nI = pI[offN];
  float mL = 0.f, mR = 0.f, mI = 0.f;
  if (lastlane) { mL = pL[offN + 1]; mR = pR[offN + 1]; mI = pI[offN + 1]; }
  offN += W;

  // 35 fully-unrolled steps (static ring slots, static bnd/syring indices)
  STEP(0, 0)  STEP(1, 1)  STEP(2, 2)  STEP(3, 3)  STEP(4, 4)
  STEP(5, 5)  STEP(6, 6)  STEP(7, 7)  STEP(8, 8)  STEP(9, 9)
  STEP(10, 0) STEP(11, 1) STEP(12, 2) STEP(13, 3) STEP(14, 4)
  STEP(15, 5) STEP(16, 6) STEP(17, 7) STEP(18, 8) STEP(19, 9)
  STEP(20, 0) STEP(21, 1) STEP(22, 2) STEP(23, 3) STEP(24, 4)
  STEP(25, 5) STEP(26, 6) STEP(27, 7) STEP(28, 8) STEP(29, 9)
  STEP(30, 0) STEP(31, 1) STEP(32, 2) STEP(33, 3) STEP(34, 4)

  // block reduction
#pragma unroll
  for (int o2 = 32; o2 > 0; o2 >>= 1) {
    accN  += __shfl_down(accN, o2);
    accGX += __shfl_down(accGX, o2);
    accGY += __shfl_down(accGY, o2);
  }
  if (lane == 0) { redN[wv] = accN; redGX[wv] = accGX; redGY[wv] = accGY; }
  __syncthreads();
  if (j == 0) {
    float n = 0.f, gx = 0.f, gy = 0.f;
#pragma unroll
    for (int w2 = 0; w2 < 8; ++w2) { n += redN[w2]; gx += redGX[w2]; gy += redGY[w2]; }
    double* p = partial + (size_t)blk * 3;
    p[0] = (double)n; p[1] = (double)gx; p[2] = (double)gy;
  }
}

__global__ __launch_bounds__(64) void ktv_reduce(const double* __restrict__ partial,
                                                 float* __restrict__ out) {
  double n = 0.0, gx = 0.0, gy = 0.0;
  for (int i = threadIdx.x; i < NBLOCKS; i += 64) {
    const double* p = partial + (size_t)i * 3;
    n += p[0]; gx += p[1]; gy += p[2];
  }
#pragma unroll
  for (int o2 = 32; o2 > 0; o2 >>= 1) {
    n  += __shfl_down(n, o2);
    gx += __shfl_down(gx, o2);
    gy += __shfl_down(gy, o2);
  }
  if (threadIdx.x == 0) {
    const double norm_loss = n / 6060144.0;          // 24*502*503
    const double grad_loss = (gx + gy) / 6279168.0;  // 24*511*512
    out[0] = (float)(1e-4 * norm_loss + grad_loss);
  }
}

extern "C" void kernel_launch(void* const* d_in, const int* in_sizes, int n_in,
                              void* d_out, int out_size, void* d_ws, size_t ws_size,
                              hipStream_t stream) {
  (void)in_sizes; (void)n_in; (void)out_size; (void)ws_size;
  const float* L = (const float*)d_in[0];
  const float* R = (const float*)d_in[1];
  const float* I = (const float*)d_in[2];
  double* partial = (double*)d_ws;   // NBLOCKS*3 doubles = 12096 B
  float* out = (float*)d_out;

  hipLaunchKernelGGL(ktv_main, dim3(NBLOCKS), dim3(512), 0, stream, L, R, I, partial);
  hipLaunchKernelGGL(ktv_reduce, dim3(1), dim3(64), 0, stream, partial, out);
}

// Round 7
// 141.724 us; speedup vs baseline: 1.1681x; 1.1681x over previous
//
#include <hip/hip_runtime.h>
#include <math.h>

// KTVLoss: inputs out_l, out_r, input_i : (8,3,512,512) fp32. Output: 1 fp32 scalar.
//
// Sx = 10x10 box sum of |dI/dh| (502x503), Sy = box sum of |dI/dw| (503x502).
// Reference pairs them by FLAT index: Sx(i,j) with Sy(i,i+j) if i+j<502 else
// Sy(i+1,i+j-502). ratio = (SxL+SyL+SxR+SyR)/(SxI+SyI+1e-4), mean over 24*502*503.
// grad part (fp32, accuracy-critical): mean|GxL+GxR-GxI| + mean|GyL+GyR-GyI|.
// norm part carries a 1e-4 weight -> computed in packed f16 (error ~1e-5 abs).
//
// One block per (image, band of RB=24 Sx rows); 512 threads = 1 per column;
// 504 blocks -> 2 blocks/CU -> ALL blocks co-resident. Horizontal 10-window
// via full-wave DPP prefix scan on packed f16 (row_shr:1/2/4/8 +
// row_bcast15/31), h = A[j+9]-A[j-1]; wave boundary (9 lanes) patched via
// tiny LDS array + readlane total. Vertical 10-window via f16x2 register ring
// (35 fully-unrolled steps => static slots). One barrier per step; all LDS
// write->read pairs barrier-separated.
//
// VGPR cap law (measured R4/R5/R6): arch-VGPR cap = 256 / min_waves_per_EU;
// no-bounds default behaves like min=4 (cap 64). This kernel needs ~90 arch
// VGPRs -> (512,8)/(512,4)/default all spilled 65-195 MB to scratch
// (WRITE_SIZE counter). __launch_bounds__(512,2): cap 128, zero spill,
// 4 waves/EU from actual usage.

namespace {

constexpr int H = 512, W = 512;
constexpr int CX = W - 10 + 1;   // 503 Sx cols (Sy has 503 rows)
constexpr int CY = W - 10;       // 502 Sy cols
constexpr int RB = 24;           // Sx rows per band
constexpr int NBANDS = (CY + RB - 1) / RB;   // 21
constexpr int NIMG = 24;
constexpr int NBLOCKS = NIMG * NBANDS;       // 504

typedef __fp16 h2 __attribute__((ext_vector_type(2)));

__device__ __forceinline__ int h2i(h2 v) { int r; __builtin_memcpy(&r, &v, 4); return r; }
__device__ __forceinline__ h2 i2h(int v) { h2 r; __builtin_memcpy(&r, &v, 4); return r; }

template <int C, int RM>
__device__ __forceinline__ int dppmov(int v) {
  return __builtin_amdgcn_update_dpp(0, v, C, RM, 0xf, true);
}
// full 64-lane inclusive prefix sum of a f16x2 pack (pure VALU)
__device__ __forceinline__ h2 scan64(h2 v) {
  v += i2h(dppmov<0x111, 0xf>(h2i(v)));  // row_shr:1
  v += i2h(dppmov<0x112, 0xf>(h2i(v)));  // row_shr:2
  v += i2h(dppmov<0x114, 0xf>(h2i(v)));  // row_shr:4
  v += i2h(dppmov<0x118, 0xf>(h2i(v)));  // row_shr:8
  v += i2h(dppmov<0x142, 0xa>(h2i(v)));  // row_bcast15 -> rows 1,3
  v += i2h(dppmov<0x143, 0xc>(h2i(v)));  // row_bcast31 -> rows 2,3
  return v;
}
__device__ __forceinline__ float wshl1(float v) {  // lane i <- lane i+1
  return __int_as_float(__builtin_amdgcn_update_dpp(0, __float_as_int(v), 0x130, 0xf, 0xf, true));
}

}  // namespace

// One streaming step; S (step) and U (ring slot = S%10) are literals.
#define STEP(S, U)                                                                \
  {                                                                               \
    constexpr int s_ = (S);                                                       \
    const int r = i0 + s_;                                                        \
    const float xl = nL, xr = nR, xi = nI;                                        \
    const float x1l = mL, x1r = mR, x1i = mI;                                     \
    if (r + 1 < H) { /* prefetch next row (wave-uniform guard) */                 \
      nL = pL[offN]; nR = pR[offN]; nI = pI[offN];                                \
      if (lastlane) { mL = pL[offN + 1]; mR = pR[offN + 1]; mI = pI[offN + 1]; }  \
      offN += W;                                                                  \
    }                                                                             \
    float nxl = wshl1(xl), nxr = wshl1(xr), nxi = wshl1(xi);                      \
    if (lastlane) { nxl = x1l; nxr = x1r; nxi = x1i; }                            \
    const float gyl = nxl - xl, gyr = nxr - xr, gyi = nxi - xi;                   \
    const float gxl = xl - prevL, gxr = xr - prevR, gxi = xi - prevI;             \
    prevL = xl; prevR = xr; prevI = xi;                                           \
    if (r < gyEnd && j < W - 1) accGY += fabsf(gyl + gyr - gyi);                  \
    if (s_ > 0 && (r - 1) < gxEnd) accGX += fabsf(gxl + gxr - gxi);               \
    float yn = fabsf(gyl) + fabsf(gyr), yd = fabsf(gyi);                          \
    float xn = fabsf(gxl) + fabsf(gxr), xd = fabsf(gxi);                          \
    if (j == W - 1) { yn = 0.f; yd = 0.f; }                                       \
    if (r >= H) { yn = 0.f; yd = 0.f; xn = 0.f; xd = 0.f; }                       \
    const h2 Y = __builtin_amdgcn_cvt_pkrtz(yn, yd);                              \
    h2 X = (h2)(__fp16)0;                                                         \
    if (s_ != 0) X = __builtin_amdgcn_cvt_pkrtz(xn, xd);                          \
    const h2 AY = scan64(Y), AX = scan64(X);                                      \
    const h2 eY = i2h(dppmov<0x138, 0xf>(h2i(AY)));  /* A[j-1], wave_shr:1 */     \
    const h2 eX = i2h(dppmov<0x138, 0xf>(h2i(AX)));                               \
    const h2 TY = i2h(__builtin_amdgcn_readlane(h2i(AY), 63));                    \
    const h2 TX = i2h(__builtin_amdgcn_readlane(h2i(AX), 63));                    \
    h2 hY = i2h(__shfl(h2i(AY), lane9)) - eY;        /* A[j+9]-A[j-1] */          \
    h2 hX = i2h(__shfl(h2i(AX), lane9)) - eX;                                     \
    const h2 pY = TY - eY, pX = TX - eX;                                          \
    if (lane <= 8) bnd[s_ & 1][wv][lane] = make_int2(h2i(AY), h2i(AX));           \
    __syncthreads();                                                              \
    if (patch) { /* lanes 55..63: window spills into next wave */                 \
      const int2 Ap = bnd[s_ & 1][wv + 1][lane - 55];                             \
      hY = i2h(Ap.x) + pY;                                                        \
      hX = i2h(Ap.y) + pX;                                                        \
    }                                                                             \
    if (s_ >= 11) { /* runX pre-update == Sx row r-11; Sy rows r-11,r-10 ready */ \
      const int iX = r - 11;                                                      \
      if (iX < sxEnd && j < CX) {                                                 \
        int jy = iX + j, rw = iX;                                                 \
        if (jy >= CY) { jy -= CY; ++rw; }                                         \
        const h2 sy = i2h(syring[rw & 3][jy]);                                    \
        const float num = (float)runX.x + (float)sy.x;                            \
        const float den = (float)runX.y + (float)sy.y + 1e-4f;                    \
        accN += num * __builtin_amdgcn_rcpf(den);                                 \
      }                                                                           \
    }                                                                             \
    runY += hY - histY[U]; histY[U] = hY;                                         \
    runX += hX - histX[U]; histX[U] = hX;                                         \
    if (s_ >= 9) {                                                                \
      const int iY = r - 9;                                                       \
      if (iY <= sxEnd && j < CY) syring[iY & 3][j] = h2i(runY);                   \
    }                                                                             \
  }

__global__ __launch_bounds__(512, 2) void ktv_main(const float* __restrict__ L,
                                                   const float* __restrict__ R,
                                                   const float* __restrict__ I,
                                                   double* __restrict__ partial) {
  const int blk = blockIdx.x;
  const int img = blk / NBANDS;
  const int band = blk % NBANDS;
  const int i0 = band * RB;
  const int j = threadIdx.x;  // column
  const int lane = j & 63;
  const int wv = j >> 6;
  const int lane9 = lane + 9;
  const bool lastlane = (lane == 63) && (j < W - 1);
  const bool patch = (lane >= 55) && (wv < 7);

  const bool lastb = (band == NBANDS - 1);
  const int gyEnd = lastb ? H : (i0 + RB);        // Gy rows owned: [i0, gyEnd)
  const int gxEnd = lastb ? (H - 1) : (i0 + RB);  // Gx rows owned: [i0, gxEnd)
  const int sxEnd = lastb ? CY : (i0 + RB);       // Sx rows owned: [i0, sxEnd)

  const size_t base = (size_t)img * (H * W);
  const float* pL = L + base;
  const float* pR = R + base;
  const float* pI = I + base;

  __shared__ int syring[4][CY];    // completed Sy rows (f16x2 n,d), depth-4 ring
  __shared__ int2 bnd[2][8][9];    // per-wave lanes 0..8 scan prefix (Y,X packs)
  __shared__ float redN[8], redGX[8], redGY[8];

  h2 histY[10], histX[10];
#pragma unroll
  for (int t = 0; t < 10; ++t) { histY[t] = (h2)(__fp16)0; histX[t] = (h2)(__fp16)0; }
  h2 runY = (h2)(__fp16)0, runX = (h2)(__fp16)0;
  float accN = 0.f, accGX = 0.f, accGY = 0.f;
  float prevL = 0.f, prevR = 0.f, prevI = 0.f;

  // prologue: load row i0 (+ lane-63 col j+1 patch values)
  int offN = i0 * W + j;
  float nL = pL[offN], nR = pR[offN], nI = pI[offN];
  float mL = 0.f, mR = 0.f, mI = 0.f;
  if (lastlane) { mL = pL[offN + 1]; mR = pR[offN + 1]; mI = pI[offN + 1]; }
  offN += W;

  // 35 fully-unrolled steps (static ring slots, static bnd/syring indices)
  STEP(0, 0)  STEP(1, 1)  STEP(2, 2)  STEP(3, 3)  STEP(4, 4)
  STEP(5, 5)  STEP(6, 6)  STEP(7, 7)  STEP(8, 8)  STEP(9, 9)
  STEP(10, 0) STEP(11, 1) STEP(12, 2) STEP(13, 3) STEP(14, 4)
  STEP(15, 5) STEP(16, 6) STEP(17, 7) STEP(18, 8) STEP(19, 9)
  STEP(20, 0) STEP(21, 1) STEP(22, 2) STEP(23, 3) STEP(24, 4)
  STEP(25, 5) STEP(26, 6) STEP(27, 7) STEP(28, 8) STEP(29, 9)
  STEP(30, 0) STEP(31, 1) STEP(32, 2) STEP(33, 3) STEP(34, 4)

  // block reduction
#pragma unroll
  for (int o2 = 32; o2 > 0; o2 >>= 1) {
    accN  += __shfl_down(accN, o2);
    accGX += __shfl_down(accGX, o2);
    accGY += __shfl_down(accGY, o2);
  }
  if (lane == 0) { redN[wv] = accN; redGX[wv] = accGX; redGY[wv] = accGY; }
  __syncthreads();
  if (j == 0) {
    float n = 0.f, gx = 0.f, gy = 0.f;
#pragma unroll
    for (int w2 = 0; w2 < 8; ++w2) { n += redN[w2]; gx += redGX[w2]; gy += redGY[w2]; }
    double* p = partial + (size_t)blk * 3;
    p[0] = (double)n; p[1] = (double)gx; p[2] = (double)gy;
  }
}

__global__ __launch_bounds__(64) void ktv_reduce(const double* __restrict__ partial,
                                                 float* __restrict__ out) {
  double n = 0.0, gx = 0.0, gy = 0.0;
  for (int i = threadIdx.x; i < NBLOCKS; i += 64) {
    const double* p = partial + (size_t)i * 3;
    n += p[0]; gx += p[1]; gy += p[2];
  }
#pragma unroll
  for (int o2 = 32; o2 > 0; o2 >>= 1) {
    n  += __shfl_down(n, o2);
    gx += __shfl_down(gx, o2);
    gy += __shfl_down(gy, o2);
  }
  if (threadIdx.x == 0) {
    const double norm_loss = n / 6060144.0;          // 24*502*503
    const double grad_loss = (gx + gy) / 6279168.0;  // 24*511*512
    out[0] = (float)(1e-4 * norm_loss + grad_loss);
  }
}

extern "C" void kernel_launch(void* const* d_in, const int* in_sizes, int n_in,
                              void* d_out, int out_size, void* d_ws, size_t ws_size,
                              hipStream_t stream) {
  (void)in_sizes; (void)n_in; (void)out_size; (void)ws_size;
  const float* L = (const float*)d_in[0];
  const float* R = (const float*)d_in[1];
  const float* I = (const float*)d_in[2];
  double* partial = (double*)d_ws;   // NBLOCKS*3 doubles = 12096 B
  float* out = (float*)d_out;

  hipLaunchKernelGGL(ktv_main, dim3(NBLOCKS), dim3(512), 0, stream, L, R, I, partial);
  hipLaunchKernelGGL(ktv_reduce, dim3(1), dim3(64), 0, stream, partial, out);
}